// Round 14
// baseline (350.647 us; speedup 1.0000x reference)
//
#include <hip/hip_runtime.h>
#include <hip/hip_fp16.h>
#include <stdint.h>
#include <math.h>

#define BB 8
#define NN 2048
#define KK 32
#define MM (BB*NN)      // 16384 points total
#define LL (MM*KK)      // 524288 gathered rows
#define NBLK 2048       // partial-stat blocks (estats grid == local grid == 2048)
static constexpr float EPS = 1e-5f;

typedef _Float16 half8v __attribute__((ext_vector_type(8)));
typedef _Float16 half2v __attribute__((ext_vector_type(2)));
typedef float  f32x4   __attribute__((ext_vector_type(4)));
typedef unsigned int u32;
typedef unsigned long long u64;
typedef unsigned short u16;

__device__ inline u16 f2h(float f) {            // f32 -> f16 bits (RNE)
    return __half_as_ushort(__float2half(f));
}
__device__ inline u32 f2h2(float lo, float hi) { // 2xf32 -> packed 2xf16
    __half2 h = __floats2half2_rn(lo, hi);
    return *reinterpret_cast<u32*>(&h);
}

// Half-wave (32-lane) u32 min-reduce via DPP: shr1,2,4,8 + row_bcast15.
// Result: lane 31 holds min(lanes 0..31), lane 63 holds min(lanes 32..63).
__device__ inline u32 dpp_min_half_u32(u32 v) {
    u32 t;
    t = (u32)__builtin_amdgcn_update_dpp((int)v, (int)v, 0x111, 0xf, 0xf, false); v = t < v ? t : v;
    t = (u32)__builtin_amdgcn_update_dpp((int)v, (int)v, 0x112, 0xf, 0xf, false); v = t < v ? t : v;
    t = (u32)__builtin_amdgcn_update_dpp((int)v, (int)v, 0x114, 0xf, 0xf, false); v = t < v ? t : v;
    t = (u32)__builtin_amdgcn_update_dpp((int)v, (int)v, 0x118, 0xf, 0xf, false); v = t < v ? t : v;
    t = (u32)__builtin_amdgcn_update_dpp((int)v, (int)v, 0x142, 0xf, 0xf, false); v = t < v ? t : v;
    return v;
}

// Distance bits, explicit fmaf chain so BOTH call sites produce identical bits.
__device__ inline u32 distbits(const float* __restrict__ xb,
                               float qx, float qy, float qz, float sqn,
                               int n, int j) {
    const float* pj = xb + j*3;
    float x0 = pj[0], x1 = pj[1], x2 = pj[2];
    float sqj = fmaf(x2, x2, fmaf(x1, x1, x0*x0));
    float dot = fmaf(x2, qz, fmaf(x1, qy, x0*qx));
    float d = fmaf(-2.0f, dot, sqn + sqj);
    d = (j == n) ? 0.0f : fmaxf(d, 0.0f);
    return __float_as_uint(d);
}

// ---------------- workspace layout (float offsets; u/v regions half-used as f16) ----
#define OFF_IDX   0                        // int[LL]
#define OFF_Y1    (LL)                     // float[MM*64]   } Y1+Y2 contiguous = M1 region
#define OFF_Y2    (OFF_Y1 + MM*64)         // float[MM*64]   } (dead after uv1)
#define OFF_U     (OFF_Y2 + MM*64)         // u16[MM*128] (in float[MM*128] region)
#define OFF_V     (OFF_U + MM*128)         // u16[MM*128]
#define OFF_F2    (OFF_V + MM*128)         // float[MM*128]; M2
#define OFF_PS    (OFF_F2 + MM*128)        // float[128*NBLK] channel-major
#define OFF_PS2   (OFF_PS + 2048*128)      // float[128*NBLK]
#define OFF_AB    (OFF_PS2 + 2048*128)     // float[1536]

// ---------------- kNN v3: zero-LDS, 2 queries/wave, per-lane min4 cache -----------
__global__ __launch_bounds__(256) void knn_kernel(const float* __restrict__ x,
                                                  int* __restrict__ idx_out) {
    const int t    = threadIdx.x;
    const int lane = t & 63;
    const int hh   = (lane >> 5) & 1;
    const int rl   = lane & 31;
    const int wv   = t >> 6;
    const int q    = blockIdx.x * 8 + wv*2 + hh;
    const int b    = q >> 11;
    const int n    = q & (NN - 1);

    const float* xb = x + (size_t)b * NN * 3;
    const float qx = xb[n*3], qy = xb[n*3+1], qz = xb[n*3+2];
    const float sqn = fmaf(qz, qz, fmaf(qy, qy, qx*qx));

    u64 k1 = ~0ULL, k2 = ~0ULL, k3 = ~0ULL, k4 = ~0ULL;
    #pragma unroll 8
    for (int s = 0; s < 64; ++s) {
        int j = s*32 + rl;
        u32 db = distbits(xb, qx, qy, qz, sqn, n, j);
        u64 key = ((u64)db << 32) | (u32)j;
        if (key < k4) {
            k4 = key;
            if (k4 < k3) { u64 tm = k3; k3 = k4; k4 = tm; }
            if (k3 < k2) { u64 tm = k2; k2 = k3; k3 = tm; }
            if (k2 < k1) { u64 tm = k1; k1 = k2; k2 = tm; }
        }
    }

    u64 removed = 0;
    const int out_base = q * KK;
    const int gbase    = b * NN;
    #pragma unroll 1
    for (int it = 0; it < KK; ++it) {
        u32 d1 = (u32)(k1 >> 32);
        u32 dm = dpp_min_half_u32(d1);
        u32 gd0 = (u32)__builtin_amdgcn_readlane((int)dm, 31);
        u32 gd1 = (u32)__builtin_amdgcn_readlane((int)dm, 63);
        u32 gdm = hh ? gd1 : gd0;
        u64 mask = __ballot(d1 == gdm);
        u32 lowm  = (u32)mask;
        u32 highm = (u32)(mask >> 32);
        int wl0 = __ffs(lowm) - 1;
        int wl1 = 32 + __ffs(highm) - 1;
        u32 gj0 = (u32)__builtin_amdgcn_readlane((int)(u32)k1, wl0);
        u32 gj1 = (u32)__builtin_amdgcn_readlane((int)(u32)k1, wl1);
        if (__popc(lowm) > 1 || __popc(highm) > 1) {   // exact distance tie (rare)
            u32 jc = (d1 == gdm) ? (u32)k1 : 0xFFFFFFFFu;
            u32 jm = dpp_min_half_u32(jc);
            u32 f0 = (u32)__builtin_amdgcn_readlane((int)jm, 31);
            u32 f1 = (u32)__builtin_amdgcn_readlane((int)jm, 63);
            if (__popc(lowm)  > 1) gj0 = f0;
            if (__popc(highm) > 1) gj1 = f1;
        }
        u32 gjm = hh ? gj1 : gj0;
        if (rl == 0) idx_out[out_base + it] = gbase + (int)gjm;
        int mywl = (int)(gjm & 31u);
        int mysw = (int)(gjm >> 5);
        if (rl == mywl) {
            removed |= (1ull << mysw);
            k1 = k2; k2 = k3; k3 = k4; k4 = ~0ULL;
        }
        int wlane0 = (int)(gj0 & 31u);
        int wlane1 = 32 + (int)(gj1 & 31u);
        u32 k1hi = (u32)(k1 >> 32);
        u32 h0 = (u32)__builtin_amdgcn_readlane((int)k1hi, wlane0);
        u32 h1 = (u32)__builtin_amdgcn_readlane((int)k1hi, wlane1);
        if (h0 == 0xFFFFFFFFu || h1 == 0xFFFFFFFFu) {
            u32 rem_lo = (u32)removed, rem_hi = (u32)(removed >> 32);
            u32 rlo0 = (u32)__builtin_amdgcn_readlane((int)rem_lo, wlane0);
            u32 rhi0 = (u32)__builtin_amdgcn_readlane((int)rem_hi, wlane0);
            u32 rlo1 = (u32)__builtin_amdgcn_readlane((int)rem_lo, wlane1);
            u32 rhi1 = (u32)__builtin_amdgcn_readlane((int)rem_hi, wlane1);
            u32 wlo = hh ? rlo1 : rlo0;
            u32 whi = hh ? rhi1 : rhi0;
            int rwl = hh ? (int)(gj1 & 31u) : (int)(gj0 & 31u);
            u32 dA = distbits(xb, qx, qy, qz, sqn, n, rl*32 + rwl);
            u32 dB = distbits(xb, qx, qy, qz, sqn, n, (rl + 32)*32 + rwl);
            if ((wlo >> rl) & 1u) dA = 0xFFFFFFFFu;
            if ((whi >> rl) & 1u) dB = 0xFFFFFFFFu;
            u64 kA = ((u64)dA << 32) | (u32)rl;
            u64 kB = ((u64)dB << 32) | (u32)(rl + 32);
            u64 nk[4];
            #pragma unroll
            for (int e = 0; e < 4; ++e) {
                u32 da  = (u32)(kA >> 32);
                u32 dbv = (u32)(kB >> 32);
                u32 dloc = da < dbv ? da : dbv;
                u32 dmv = dpp_min_half_u32(dloc);
                u32 e0 = (u32)__builtin_amdgcn_readlane((int)dmv, 31);
                u32 e1 = (u32)__builtin_amdgcn_readlane((int)dmv, 63);
                u32 gdr = hh ? e1 : e0;
                u32 scand = 0xFFFFFFFFu;
                if (dbv == gdr) scand = (u32)kB;
                if (da  == gdr) scand = (u32)kA;
                u32 smv = dpp_min_half_u32(scand);
                u32 s0v = (u32)__builtin_amdgcn_readlane((int)smv, 31);
                u32 s1v = (u32)__builtin_amdgcn_readlane((int)smv, 63);
                u32 smine = hh ? s1v : s0v;
                nk[e] = ((u64)gdr << 32) | smine;
                if ((u32)kA == smine) kA = ~0ULL;
                if ((u32)kB == smine) kB = ~0ULL;
            }
            if (rl == rwl) {
                k1 = ((u64)(nk[0] >> 32) << 32) | (u32)((u32)nk[0]*32u + (u32)rwl);
                k2 = ((u64)(nk[1] >> 32) << 32) | (u32)((u32)nk[1]*32u + (u32)rwl);
                k3 = ((u64)(nk[2] >> 32) << 32) | (u32)((u32)nk[2]*32u + (u32)rwl);
                k4 = ((u64)(nk[3] >> 32) << 32) | (u32)((u32)nk[3]*32u + (u32)rwl);
            }
        }
    }
}

// ---------------- encoder layer 1: y1 = x @ W_e1^T  (3 -> 64) ----------------
__global__ __launch_bounds__(256) void enc1_kernel(const float* __restrict__ x,
                                                   const float* __restrict__ W,
                                                   float* __restrict__ y1) {
    __shared__ float w[192];
    if (threadIdx.x < 192) w[threadIdx.x] = W[threadIdx.x];
    __syncthreads();
    int lin = blockIdx.x*256 + threadIdx.x;
    int row = lin >> 6, d = lin & 63;
    float x0 = x[row*3], x1 = x[row*3+1], x2 = x[row*3+2];
    y1[lin] = x0*w[d*3] + x1*w[d*3+1] + x2*w[d*3+2];
}

// ---------------- per-channel BN stats over M rows -> a,b coeffs ----------------
__global__ __launch_bounds__(256) void colstats_kernel(const float* __restrict__ y,
                                                       int Mrows, int C,
                                                       const float* __restrict__ gamma,
                                                       const float* __restrict__ beta,
                                                       float* __restrict__ a_out,
                                                       float* __restrict__ b_out) {
    __shared__ float rs[256], rs2[256];
    int c = blockIdx.x;
    float s = 0.f, s2 = 0.f;
    for (int r = threadIdx.x; r < Mrows; r += 256) {
        float vv = y[r*C + c];
        s += vv; s2 += vv*vv;
    }
    rs[threadIdx.x] = s; rs2[threadIdx.x] = s2;
    __syncthreads();
    for (int off = 128; off > 0; off >>= 1) {
        if (threadIdx.x < off) {
            rs[threadIdx.x]  += rs[threadIdx.x+off];
            rs2[threadIdx.x] += rs2[threadIdx.x+off];
        }
        __syncthreads();
    }
    if (threadIdx.x == 0) {
        float mean = rs[0] / (float)Mrows;
        float var  = rs2[0] / (float)Mrows - mean*mean;
        float a = gamma[c] * rsqrtf(var + EPS);
        a_out[c] = a;
        b_out[c] = beta[c] - mean*a;
    }
}

// ---------------- encoder layer 2: y2 = relu(bn(y1)) @ W_e2^T (64 -> 64) ----------------
__global__ __launch_bounds__(256) void enc2_kernel(const float* __restrict__ y1,
                                                   const float* __restrict__ a,
                                                   const float* __restrict__ b,
                                                   const float* __restrict__ W,
                                                   float* __restrict__ y2) {
    __shared__ float wt[4096];
    __shared__ float f[256];
    for (int i = threadIdx.x; i < 4096; i += 256)
        wt[(i & 63)*64 + (i >> 6)] = W[i];
    int lin = blockIdx.x*256 + threadIdx.x;
    int c0 = threadIdx.x & 63;
    f[threadIdx.x] = fmaxf(a[c0]*y1[lin] + b[c0], 0.0f);
    __syncthreads();
    int rloc = threadIdx.x >> 6, d = threadIdx.x & 63;
    const float* fr = f + rloc*64;
    float acc = 0.f;
    #pragma unroll 8
    for (int c = 0; c < 64; ++c) acc += fr[c] * wt[c*64 + d];
    y2[lin] = acc;
}

// ---------------- uv via MFMA f16, register-B converted directly from f32 W --------
template<int CIN, bool APPLY_BN>
__global__ __launch_bounds__(256) void uv_mfma_kernel(
        const float* __restrict__ fin,
        const float* __restrict__ a, const float* __restrict__ b,
        const float* __restrict__ W,    // 128 x 2*CIN f32
        u16* __restrict__ u, u16* __restrict__ v) {
    constexpr int PAD = CIN + 8;
    __shared__ u16 alds[32*PAD];
    const int t  = threadIdx.x;
    const int l  = t & 63;
    const int w  = t >> 6;      // wave -> output cols 64w..64w+63
    const int lr = l & 15;
    const int kg = l >> 4;

    // B fragments: output row dcol = w*64+ct*16+lr; col chunk kk*32+kg*8
    half8v bfrag[4][CIN/32];
    #pragma unroll
    for (int ct = 0; ct < 4; ++ct) {
        const int dcol = w*64 + ct*16 + lr;
        #pragma unroll
        for (int kk = 0; kk < CIN/32; ++kk) {
            const int c = kk*32 + kg*8;
            half8v h;
            if (dcol < 128) {               // wave-uniform branch
                const float* wp = W + (size_t)dcol*2*CIN + c;
                float4 w0 = *(const float4*)wp;
                float4 w1 = *(const float4*)(wp + 4);
                h[0] = (_Float16)w0.x; h[1] = (_Float16)w0.y;
                h[2] = (_Float16)w0.z; h[3] = (_Float16)w0.w;
                h[4] = (_Float16)w1.x; h[5] = (_Float16)w1.y;
                h[6] = (_Float16)w1.z; h[7] = (_Float16)w1.w;
            } else {
                const float* wr = W + (size_t)(dcol-128)*2*CIN;
                float4 l0 = *(const float4*)(wr + c);
                float4 l1 = *(const float4*)(wr + c + 4);
                float4 r0 = *(const float4*)(wr + CIN + c);
                float4 r1 = *(const float4*)(wr + CIN + c + 4);
                h[0] = (_Float16)(r0.x - l0.x); h[1] = (_Float16)(r0.y - l0.y);
                h[2] = (_Float16)(r0.z - l0.z); h[3] = (_Float16)(r0.w - l0.w);
                h[4] = (_Float16)(r1.x - l1.x); h[5] = (_Float16)(r1.y - l1.y);
                h[6] = (_Float16)(r1.z - l1.z); h[7] = (_Float16)(r1.w - l1.w);
            }
            bfrag[ct][kk] = h;
        }
    }

    // stage A tile (32 rows), paired-u32 LDS writes, bn fused
    const int r0 = blockIdx.x * 32;
    for (int i2 = t; i2 < 32*(CIN/2); i2 += 256) {
        int r = i2 / (CIN/2);
        int c = (i2 & (CIN/2 - 1)) * 2;
        float2 vv = *(const float2*)&fin[(size_t)(r0 + r)*CIN + c];
        if (APPLY_BN) {
            float2 av = *(const float2*)&a[c];
            float2 bv = *(const float2*)&b[c];
            vv.x = fmaxf(av.x*vv.x + bv.x, 0.f);
            vv.y = fmaxf(av.y*vv.y + bv.y, 0.f);
        }
        *(u32*)&alds[r*PAD + c] = f2h2(vv.x, vv.y);
    }
    __syncthreads();

    f32x4 acc[2][4];
    #pragma unroll
    for (int rt = 0; rt < 2; ++rt)
        #pragma unroll
        for (int ct = 0; ct < 4; ++ct)
            acc[rt][ct] = (f32x4){0.f, 0.f, 0.f, 0.f};
    #pragma unroll
    for (int kk = 0; kk < CIN/32; ++kk) {
        const int ko = kk*32 + kg*8;
        half8v a0 = *(const half8v*)&alds[lr*PAD + ko];
        half8v a1 = *(const half8v*)&alds[(16 + lr)*PAD + ko];
        #pragma unroll
        for (int ct = 0; ct < 4; ++ct) {
            acc[0][ct] = __builtin_amdgcn_mfma_f32_16x16x32_f16(a0, bfrag[ct][kk], acc[0][ct], 0, 0, 0);
            acc[1][ct] = __builtin_amdgcn_mfma_f32_16x16x32_f16(a1, bfrag[ct][kk], acc[1][ct], 0, 0, 0);
        }
    }
    // write: C layout col=l&15, row=(l>>4)*4+e  [m89-verified]
    #pragma unroll
    for (int rt = 0; rt < 2; ++rt) {
        #pragma unroll
        for (int ct = 0; ct < 4; ++ct) {
            int col = w*64 + ct*16 + lr;            // wave-uniform side of 128 split
            u16* dst = (col < 128) ? u : v;
            int cc = col & 127;
            #pragma unroll
            for (int e = 0; e < 4; ++e) {
                int row = r0 + rt*16 + kg*4 + e;
                dst[(size_t)row*128 + cc] = f2h(acc[rt][ct][e]);
            }
        }
    }
}

// ---------------- stats of e = u[idx] + v over all (b,n,k), per channel (f16 in) ----
__global__ __launch_bounds__(256) void estats_kernel(const u16* __restrict__ u,
                                                     const u16* __restrict__ v,
                                                     const int* __restrict__ idx,
                                                     float* __restrict__ pS,
                                                     float* __restrict__ pS2) {
    __shared__ float red[4][132];
    const int t = threadIdx.x;
    const int l = t & 63;
    const int g = t >> 6;
    const int c2 = l*2;
    const int row0 = blockIdx.x * 256;
    float s0=0.f, s1=0.f, q0=0.f, q1=0.f;
    #pragma unroll 4
    for (int r = 0; r < 64; ++r) {
        int row = row0 + r*4 + g;
        int n = row >> 5;
        int j = idx[row];
        half2v uh = *(const half2v*)&u[(size_t)j*128 + c2];
        half2v vh = *(const half2v*)&v[(size_t)n*128 + c2];
        half2v eh = uh + vh;                    // v_pk_add_f16
        float e0 = (float)eh[0];
        float e1 = (float)eh[1];
        s0 += e0; q0 += e0*e0;
        s1 += e1; q1 += e1*e1;
    }
    red[g][c2] = s0; red[g][c2+1] = s1;
    __syncthreads();
    if (t < 128) pS[t*NBLK + blockIdx.x] = red[0][t]+red[1][t]+red[2][t]+red[3][t];
    __syncthreads();
    red[g][c2] = q0; red[g][c2+1] = q1;
    __syncthreads();
    if (t < 128) pS2[t*NBLK + blockIdx.x] = red[0][t]+red[1][t]+red[2][t]+red[3][t];
}

// ---------------- finalize BN coeffs: 128 blocks, coalesced channel-major reads -----
__global__ __launch_bounds__(256) void reduce_ab_kernel(const float* __restrict__ pS,
                                                        const float* __restrict__ pS2,
                                                        int nblk, float count,
                                                        const float* __restrict__ gamma,
                                                        const float* __restrict__ beta,
                                                        float* __restrict__ a_out,
                                                        float* __restrict__ b_out) {
    __shared__ double rs[256], rs2[256];
    const int c = blockIdx.x;
    const int t = threadIdx.x;
    double s = 0.0, s2 = 0.0;
    for (int i = t; i < nblk; i += 256) {
        s  += (double)pS [c*NBLK + i];
        s2 += (double)pS2[c*NBLK + i];
    }
    rs[t] = s; rs2[t] = s2;
    __syncthreads();
    for (int off = 128; off > 0; off >>= 1) {
        if (t < off) { rs[t] += rs[t+off]; rs2[t] += rs2[t+off]; }
        __syncthreads();
    }
    if (t == 0) {
        double mean = rs[0] / (double)count;
        double var  = rs2[0] / (double)count - mean*mean;
        float a = gamma[c] * (float)(1.0 / sqrt(var + (double)EPS));
        a_out[c] = a;
        b_out[c] = beta[c] - (float)mean * a;
    }
}

// ---------------- local_op heavy pass: bn2 stats AND per-point max in ONE pass ------
// W2 fragments in registers; act staged via packed-f16 vector math (v_pk_*).
__global__ __launch_bounds__(256, 3) void local_stats_max_kernel(
        const u16* __restrict__ u, const u16* __restrict__ v,
        const int* __restrict__ idx,
        const float* __restrict__ a1, const float* __restrict__ b1,
        const float* __restrict__ W2,          // 128x128 row-major [d][c]
        float* __restrict__ pS, float* __restrict__ pS2,
        float* __restrict__ M) {
    __shared__ u16 alds[2][32*136];   // f16 act [r][c], double-buffered (17.4 KB)
    const int t  = threadIdx.x;
    const int l  = t & 63;
    const int w  = t >> 6;       // wave 0..3 -> output cols 32w..32w+31
    const int lr = l & 15;
    const int kg = l >> 4;       // 0..3

    // B fragments global->reg (f32->f16 RNE)
    half8v bfrag[2][4];
    #pragma unroll
    for (int ct = 0; ct < 2; ++ct) {
        #pragma unroll
        for (int kk = 0; kk < 4; ++kk) {
            const float* wp = W2 + (w*32 + ct*16 + lr)*128 + kk*32 + kg*8;
            float4 w0 = *(const float4*)wp;
            float4 w1 = *(const float4*)(wp + 4);
            half8v h;
            h[0] = (_Float16)w0.x; h[1] = (_Float16)w0.y;
            h[2] = (_Float16)w0.z; h[3] = (_Float16)w0.w;
            h[4] = (_Float16)w1.x; h[5] = (_Float16)w1.y;
            h[6] = (_Float16)w1.z; h[7] = (_Float16)w1.w;
            bfrag[ct][kk] = h;
        }
    }

    const int sr = t >> 3;          // staging row 0..31
    const int sc = (t & 7) * 16;    // staging col base (16 channels)

    half2v a1h[8], b1h[8];
    #pragma unroll
    for (int i = 0; i < 8; ++i) {
        a1h[i] = (half2v){(_Float16)a1[sc + 2*i], (_Float16)a1[sc + 2*i + 1]};
        b1h[i] = (half2v){(_Float16)b1[sc + 2*i], (_Float16)b1[sc + 2*i + 1]};
    }
    const half2v zero2 = (half2v){(_Float16)0.f, (_Float16)0.f};

    float sacc[2] = {0.f, 0.f}, s2acc[2] = {0.f, 0.f};

    const int p0 = blockIdx.x * 8;

    auto stage = [&](int p, int bi) {
        int j = idx[p*KK + sr];
        const half2v* up = (const half2v*)(u + (size_t)j*128 + sc);
        const half2v* vp = (const half2v*)(v + (size_t)p*128 + sc);
        uint4 ua = *(const uint4*)up;
        uint4 ub = *(const uint4*)(up + 4);
        uint4 va = *(const uint4*)vp;
        uint4 vb = *(const uint4*)(vp + 4);
        const half2v* u2 = (const half2v*)&ua;
        const half2v* u3 = (const half2v*)&ub;
        const half2v* v2 = (const half2v*)&va;
        const half2v* v3 = (const half2v*)&vb;
        uint4 w0, w1;
        half2v* w0p = (half2v*)&w0;
        half2v* w1p = (half2v*)&w1;
        #pragma unroll
        for (int i = 0; i < 4; ++i)   // v_pk_add + v_pk_fma + v_pk_max
            w0p[i] = __builtin_elementwise_max(a1h[i]*(u2[i] + v2[i]) + b1h[i], zero2);
        #pragma unroll
        for (int i = 0; i < 4; ++i)
            w1p[i] = __builtin_elementwise_max(a1h[4+i]*(u3[i] + v3[i]) + b1h[4+i], zero2);
        *(uint4*)(void*)&alds[bi][sr*136 + sc]     = w0;
        *(uint4*)(void*)&alds[bi][sr*136 + sc + 8] = w1;
    };

    stage(p0, 0);
    __syncthreads();

    for (int g = 0; g < 8; ++g) {
        const int p = p0 + g;
        if (g < 7) stage(p + 1, (g + 1) & 1);
        const u16* ab = alds[g & 1];
        f32x4 acc[2][2];
        #pragma unroll
        for (int rt = 0; rt < 2; ++rt)
            #pragma unroll
            for (int ct = 0; ct < 2; ++ct)
                acc[rt][ct] = (f32x4){0.f, 0.f, 0.f, 0.f};
        #pragma unroll
        for (int kk = 0; kk < 4; ++kk) {
            const int ko = kk*32 + kg*8;
            half8v a0  = *(const half8v*)&ab[lr*136 + ko];
            half8v a1f = *(const half8v*)&ab[(16 + lr)*136 + ko];
            acc[0][0] = __builtin_amdgcn_mfma_f32_16x16x32_f16(a0,  bfrag[0][kk], acc[0][0], 0, 0, 0);
            acc[1][0] = __builtin_amdgcn_mfma_f32_16x16x32_f16(a1f, bfrag[0][kk], acc[1][0], 0, 0, 0);
            acc[0][1] = __builtin_amdgcn_mfma_f32_16x16x32_f16(a0,  bfrag[1][kk], acc[0][1], 0, 0, 0);
            acc[1][1] = __builtin_amdgcn_mfma_f32_16x16x32_f16(a1f, bfrag[1][kk], acc[1][1], 0, 0, 0);
        }
        #pragma unroll
        for (int ct = 0; ct < 2; ++ct) {
            float s = 0.f, qq = 0.f;
            float m = acc[0][ct][0];
            #pragma unroll
            for (int rt = 0; rt < 2; ++rt)
                #pragma unroll
                for (int e = 0; e < 4; ++e) {
                    float h = acc[rt][ct][e];
                    s += h; qq += h*h;
                    m = fmaxf(m, h);
                }
            sacc[ct] += s; s2acc[ct] += qq;
            m = fmaxf(m, __shfl_xor(m, 16, 64));
            m = fmaxf(m, __shfl_xor(m, 32, 64));
            if (l < 16) M[(size_t)p*128 + w*32 + ct*16 + lr] = m;
        }
        __syncthreads();
    }
    #pragma unroll
    for (int ct = 0; ct < 2; ++ct) {
        float s = sacc[ct], qq = s2acc[ct];
        s  += __shfl_xor(s, 16, 64);  s  += __shfl_xor(s, 32, 64);
        qq += __shfl_xor(qq, 16, 64); qq += __shfl_xor(qq, 32, 64);
        if (l < 16) {
            pS [(w*32 + ct*16 + lr)*NBLK + blockIdx.x] = s;
            pS2[(w*32 + ct*16 + lr)*NBLK + blockIdx.x] = qq;
        }
    }
}

// ---------------- finalize: out = relu(a2*M + b2), elementwise MM x 128 -------------
__global__ __launch_bounds__(256) void finalize_kernel(const float* __restrict__ M,
                                                       const float* __restrict__ a2,
                                                       const float* __restrict__ b2,
                                                       float* __restrict__ outp) {
    int i = blockIdx.x*256 + threadIdx.x;   // float4 index over MM*32
    int c = (i & 31) * 4;
    float4 av = *(const float4*)&a2[c];
    float4 bv = *(const float4*)&b2[c];
    float4 m = ((const float4*)M)[i];
    m.x = fmaxf(av.x*m.x + bv.x, 0.f);
    m.y = fmaxf(av.y*m.y + bv.y, 0.f);
    m.z = fmaxf(av.z*m.z + bv.z, 0.f);
    m.w = fmaxf(av.w*m.w + bv.w, 0.f);
    ((float4*)outp)[i] = m;
}

// ---------------- host launcher ----------------
extern "C" void kernel_launch(void* const* d_in, const int* in_sizes, int n_in,
                              void* d_out, int out_size, void* d_ws, size_t ws_size,
                              hipStream_t stream) {
    const float* x     = (const float*)d_in[0];
    const float* W_e1  = (const float*)d_in[1];
    const float* g_e1  = (const float*)d_in[2];
    const float* b_e1  = (const float*)d_in[3];
    const float* W_e2  = (const float*)d_in[4];
    const float* g_e2  = (const float*)d_in[5];
    const float* b_e2  = (const float*)d_in[6];
    const float* W_l1a = (const float*)d_in[7];
    const float* g_l1a = (const float*)d_in[8];
    const float* b_l1a = (const float*)d_in[9];
    const float* W_l1b = (const float*)d_in[10];
    const float* g_l1b = (const float*)d_in[11];
    const float* b_l1b = (const float*)d_in[12];
    const float* W_l2a = (const float*)d_in[13];
    const float* g_l2a = (const float*)d_in[14];
    const float* b_l2a = (const float*)d_in[15];
    const float* W_l2b = (const float*)d_in[16];
    const float* g_l2b = (const float*)d_in[17];
    const float* b_l2b = (const float*)d_in[18];

    float* ws   = (float*)d_ws;
    int*   idx  = (int*)(ws + OFF_IDX);
    float* y1   = ws + OFF_Y1;
    float* y2   = ws + OFF_Y2;
    u16*   u    = (u16*)(ws + OFF_U);
    u16*   v    = (u16*)(ws + OFF_V);
    float* M1   = ws + OFF_Y1;     // reuses Y1+Y2 (dead after uv1)
    float* M2   = ws + OFF_F2;
    float* pS   = ws + OFF_PS;
    float* pS2  = ws + OFF_PS2;
    float* ab   = ws + OFF_AB;
    float *a_e1 = ab,        *be1 = ab + 128,
          *a_e2 = ab + 256,  *be2 = ab + 384,
          *a_1a = ab + 512,  *b_1a = ab + 640,
          *a_1b = ab + 768,  *b_1b = ab + 896,
          *a_2a = ab + 1024, *b_2a = ab + 1152,
          *a_2b = ab + 1280, *b_2b = ab + 1408;

    knn_kernel<<<dim3(MM/8), dim3(256), 0, stream>>>(x, idx);

    enc1_kernel<<<dim3(MM*64/256), dim3(256), 0, stream>>>(x, W_e1, y1);
    colstats_kernel<<<dim3(64), dim3(256), 0, stream>>>(y1, MM, 64, g_e1, b_e1, a_e1, be1);
    enc2_kernel<<<dim3(MM*64/256), dim3(256), 0, stream>>>(y1, a_e1, be1, W_e2, y2);
    colstats_kernel<<<dim3(64), dim3(256), 0, stream>>>(y2, MM, 64, g_e2, b_e2, a_e2, be2);

    // ---- local_op 1 ----
    uv_mfma_kernel<64, true><<<dim3(MM/32), dim3(256), 0, stream>>>(y2, a_e2, be2, W_l1a, u, v);
    estats_kernel<<<dim3(LL/256), dim3(256), 0, stream>>>(u, v, idx, pS, pS2);
    reduce_ab_kernel<<<dim3(128), dim3(256), 0, stream>>>(pS, pS2, LL/256, (float)LL, g_l1a, b_l1a, a_1a, b_1a);
    local_stats_max_kernel<<<dim3(MM/8), dim3(256), 0, stream>>>(u, v, idx, a_1a, b_1a, W_l1b, pS, pS2, M1);
    reduce_ab_kernel<<<dim3(128), dim3(256), 0, stream>>>(pS, pS2, MM/8, (float)LL, g_l1b, b_l1b, a_1b, b_1b);

    // ---- local_op 2 (finalize#1 fused into uv A-load) ----
    uv_mfma_kernel<128, true><<<dim3(MM/32), dim3(256), 0, stream>>>(M1, a_1b, b_1b, W_l2a, u, v);
    estats_kernel<<<dim3(LL/256), dim3(256), 0, stream>>>(u, v, idx, pS, pS2);
    reduce_ab_kernel<<<dim3(128), dim3(256), 0, stream>>>(pS, pS2, LL/256, (float)LL, g_l2a, b_l2a, a_2a, b_2a);
    local_stats_max_kernel<<<dim3(MM/8), dim3(256), 0, stream>>>(u, v, idx, a_2a, b_2a, W_l2b, pS, pS2, M2);
    reduce_ab_kernel<<<dim3(128), dim3(256), 0, stream>>>(pS, pS2, MM/8, (float)LL, g_l2b, b_l2b, a_2b, b_2b);
    finalize_kernel<<<dim3(MM*32/256), dim3(256), 0, stream>>>(M2, a_2b, b_2b, (float*)d_out);
}

// Round 15
// 330.251 us; speedup vs baseline: 1.0618x; 1.0618x over previous
//
#include <hip/hip_runtime.h>
#include <hip/hip_fp16.h>
#include <stdint.h>
#include <math.h>

#define BB 8
#define NN 2048
#define KK 32
#define MM (BB*NN)      // 16384 points total
#define LL (MM*KK)      // 524288 gathered rows
#define NBLK 2048       // partial-stat blocks (estats grid == local grid == 2048)
static constexpr float EPS = 1e-5f;

typedef _Float16 half8v __attribute__((ext_vector_type(8)));
typedef float  f32x4   __attribute__((ext_vector_type(4)));
typedef unsigned int u32;
typedef unsigned long long u64;
typedef unsigned short u16;

__device__ inline u16 f2h(float f) {            // f32 -> f16 bits (RNE)
    return __half_as_ushort(__float2half(f));
}
__device__ inline float2 h2f2(u32 w) {          // packed 2xf16 -> 2xf32
    __half2 h = *reinterpret_cast<__half2*>(&w);
    return __half22float2(h);
}
__device__ inline u32 f2h2(float lo, float hi) { // 2xf32 -> packed 2xf16
    __half2 h = __floats2half2_rn(lo, hi);
    return *reinterpret_cast<u32*>(&h);
}

// Half-wave (32-lane) u32 min-reduce via DPP: shr1,2,4,8 + row_bcast15.
// Result: lane 31 holds min(lanes 0..31), lane 63 holds min(lanes 32..63).
__device__ inline u32 dpp_min_half_u32(u32 v) {
    u32 t;
    t = (u32)__builtin_amdgcn_update_dpp((int)v, (int)v, 0x111, 0xf, 0xf, false); v = t < v ? t : v;
    t = (u32)__builtin_amdgcn_update_dpp((int)v, (int)v, 0x112, 0xf, 0xf, false); v = t < v ? t : v;
    t = (u32)__builtin_amdgcn_update_dpp((int)v, (int)v, 0x114, 0xf, 0xf, false); v = t < v ? t : v;
    t = (u32)__builtin_amdgcn_update_dpp((int)v, (int)v, 0x118, 0xf, 0xf, false); v = t < v ? t : v;
    t = (u32)__builtin_amdgcn_update_dpp((int)v, (int)v, 0x142, 0xf, 0xf, false); v = t < v ? t : v;
    return v;
}

// Distance bits, explicit fmaf chain so BOTH call sites produce identical bits.
__device__ inline u32 distbits(const float* __restrict__ xb,
                               float qx, float qy, float qz, float sqn,
                               int n, int j) {
    const float* pj = xb + j*3;
    float x0 = pj[0], x1 = pj[1], x2 = pj[2];
    float sqj = fmaf(x2, x2, fmaf(x1, x1, x0*x0));
    float dot = fmaf(x2, qz, fmaf(x1, qy, x0*qx));
    float d = fmaf(-2.0f, dot, sqn + sqj);
    d = (j == n) ? 0.0f : fmaxf(d, 0.0f);
    return __float_as_uint(d);
}

// ---------------- workspace layout (float offsets; u/v regions half-used as f16) ----
#define OFF_IDX   0                        // int[LL]
#define OFF_Y1    (LL)                     // float[MM*64]   } Y1+Y2 contiguous = M1 region
#define OFF_Y2    (OFF_Y1 + MM*64)         // float[MM*64]   } (dead after uv1)
#define OFF_U     (OFF_Y2 + MM*64)         // u16[MM*128] (in float[MM*128] region)
#define OFF_V     (OFF_U + MM*128)         // u16[MM*128]
#define OFF_F2    (OFF_V + MM*128)         // float[MM*128]; M2
#define OFF_PS    (OFF_F2 + MM*128)        // float[128*NBLK] channel-major; W16 aliased here
#define OFF_PS2   (OFF_PS + 2048*128)      // float[128*NBLK]
#define OFF_AB    (OFF_PS2 + 2048*128)     // float[1536]

// ---------------- kNN v3: zero-LDS, 2 queries/wave, per-lane min4 cache -----------
__global__ __launch_bounds__(256) void knn_kernel(const float* __restrict__ x,
                                                  int* __restrict__ idx_out) {
    const int t    = threadIdx.x;
    const int lane = t & 63;
    const int hh   = (lane >> 5) & 1;
    const int rl   = lane & 31;
    const int wv   = t >> 6;
    const int q    = blockIdx.x * 8 + wv*2 + hh;
    const int b    = q >> 11;
    const int n    = q & (NN - 1);

    const float* xb = x + (size_t)b * NN * 3;
    const float qx = xb[n*3], qy = xb[n*3+1], qz = xb[n*3+2];
    const float sqn = fmaf(qz, qz, fmaf(qy, qy, qx*qx));

    u64 k1 = ~0ULL, k2 = ~0ULL, k3 = ~0ULL, k4 = ~0ULL;
    #pragma unroll 8
    for (int s = 0; s < 64; ++s) {
        int j = s*32 + rl;
        u32 db = distbits(xb, qx, qy, qz, sqn, n, j);
        u64 key = ((u64)db << 32) | (u32)j;
        if (key < k4) {
            k4 = key;
            if (k4 < k3) { u64 tm = k3; k3 = k4; k4 = tm; }
            if (k3 < k2) { u64 tm = k2; k2 = k3; k3 = tm; }
            if (k2 < k1) { u64 tm = k1; k1 = k2; k2 = tm; }
        }
    }

    u64 removed = 0;
    const int out_base = q * KK;
    const int gbase    = b * NN;
    #pragma unroll 1
    for (int it = 0; it < KK; ++it) {
        u32 d1 = (u32)(k1 >> 32);
        u32 dm = dpp_min_half_u32(d1);
        u32 gd0 = (u32)__builtin_amdgcn_readlane((int)dm, 31);
        u32 gd1 = (u32)__builtin_amdgcn_readlane((int)dm, 63);
        u32 gdm = hh ? gd1 : gd0;
        u64 mask = __ballot(d1 == gdm);
        u32 lowm  = (u32)mask;
        u32 highm = (u32)(mask >> 32);
        int wl0 = __ffs(lowm) - 1;
        int wl1 = 32 + __ffs(highm) - 1;
        u32 gj0 = (u32)__builtin_amdgcn_readlane((int)(u32)k1, wl0);
        u32 gj1 = (u32)__builtin_amdgcn_readlane((int)(u32)k1, wl1);
        if (__popc(lowm) > 1 || __popc(highm) > 1) {   // exact distance tie (rare)
            u32 jc = (d1 == gdm) ? (u32)k1 : 0xFFFFFFFFu;
            u32 jm = dpp_min_half_u32(jc);
            u32 f0 = (u32)__builtin_amdgcn_readlane((int)jm, 31);
            u32 f1 = (u32)__builtin_amdgcn_readlane((int)jm, 63);
            if (__popc(lowm)  > 1) gj0 = f0;
            if (__popc(highm) > 1) gj1 = f1;
        }
        u32 gjm = hh ? gj1 : gj0;
        if (rl == 0) idx_out[out_base + it] = gbase + (int)gjm;
        int mywl = (int)(gjm & 31u);
        int mysw = (int)(gjm >> 5);
        if (rl == mywl) {
            removed |= (1ull << mysw);
            k1 = k2; k2 = k3; k3 = k4; k4 = ~0ULL;
        }
        int wlane0 = (int)(gj0 & 31u);
        int wlane1 = 32 + (int)(gj1 & 31u);
        u32 k1hi = (u32)(k1 >> 32);
        u32 h0 = (u32)__builtin_amdgcn_readlane((int)k1hi, wlane0);
        u32 h1 = (u32)__builtin_amdgcn_readlane((int)k1hi, wlane1);
        if (h0 == 0xFFFFFFFFu || h1 == 0xFFFFFFFFu) {
            u32 rem_lo = (u32)removed, rem_hi = (u32)(removed >> 32);
            u32 rlo0 = (u32)__builtin_amdgcn_readlane((int)rem_lo, wlane0);
            u32 rhi0 = (u32)__builtin_amdgcn_readlane((int)rem_hi, wlane0);
            u32 rlo1 = (u32)__builtin_amdgcn_readlane((int)rem_lo, wlane1);
            u32 rhi1 = (u32)__builtin_amdgcn_readlane((int)rem_hi, wlane1);
            u32 wlo = hh ? rlo1 : rlo0;
            u32 whi = hh ? rhi1 : rhi0;
            int rwl = hh ? (int)(gj1 & 31u) : (int)(gj0 & 31u);
            u32 dA = distbits(xb, qx, qy, qz, sqn, n, rl*32 + rwl);
            u32 dB = distbits(xb, qx, qy, qz, sqn, n, (rl + 32)*32 + rwl);
            if ((wlo >> rl) & 1u) dA = 0xFFFFFFFFu;
            if ((whi >> rl) & 1u) dB = 0xFFFFFFFFu;
            u64 kA = ((u64)dA << 32) | (u32)rl;
            u64 kB = ((u64)dB << 32) | (u32)(rl + 32);
            u64 nk[4];
            #pragma unroll
            for (int e = 0; e < 4; ++e) {
                u32 da  = (u32)(kA >> 32);
                u32 dbv = (u32)(kB >> 32);
                u32 dloc = da < dbv ? da : dbv;
                u32 dmv = dpp_min_half_u32(dloc);
                u32 e0 = (u32)__builtin_amdgcn_readlane((int)dmv, 31);
                u32 e1 = (u32)__builtin_amdgcn_readlane((int)dmv, 63);
                u32 gdr = hh ? e1 : e0;
                u32 scand = 0xFFFFFFFFu;
                if (dbv == gdr) scand = (u32)kB;
                if (da  == gdr) scand = (u32)kA;
                u32 smv = dpp_min_half_u32(scand);
                u32 s0v = (u32)__builtin_amdgcn_readlane((int)smv, 31);
                u32 s1v = (u32)__builtin_amdgcn_readlane((int)smv, 63);
                u32 smine = hh ? s1v : s0v;
                nk[e] = ((u64)gdr << 32) | smine;
                if ((u32)kA == smine) kA = ~0ULL;
                if ((u32)kB == smine) kB = ~0ULL;
            }
            if (rl == rwl) {
                k1 = ((u64)(nk[0] >> 32) << 32) | (u32)((u32)nk[0]*32u + (u32)rwl);
                k2 = ((u64)(nk[1] >> 32) << 32) | (u32)((u32)nk[1]*32u + (u32)rwl);
                k3 = ((u64)(nk[2] >> 32) << 32) | (u32)((u32)nk[2]*32u + (u32)rwl);
                k4 = ((u64)(nk[3] >> 32) << 32) | (u32)((u32)nk[3]*32u + (u32)rwl);
            }
        }
    }
}

// ---------------- encoder layer 1: y1 = x @ W_e1^T  (3 -> 64) ----------------
__global__ __launch_bounds__(256) void enc1_kernel(const float* __restrict__ x,
                                                   const float* __restrict__ W,
                                                   float* __restrict__ y1) {
    __shared__ float w[192];
    if (threadIdx.x < 192) w[threadIdx.x] = W[threadIdx.x];
    __syncthreads();
    int lin = blockIdx.x*256 + threadIdx.x;
    int row = lin >> 6, d = lin & 63;
    float x0 = x[row*3], x1 = x[row*3+1], x2 = x[row*3+2];
    y1[lin] = x0*w[d*3] + x1*w[d*3+1] + x2*w[d*3+2];
}

// ---------------- per-channel BN stats over M rows -> a,b coeffs ----------------
__global__ __launch_bounds__(256) void colstats_kernel(const float* __restrict__ y,
                                                       int Mrows, int C,
                                                       const float* __restrict__ gamma,
                                                       const float* __restrict__ beta,
                                                       float* __restrict__ a_out,
                                                       float* __restrict__ b_out) {
    __shared__ float rs[256], rs2[256];
    int c = blockIdx.x;
    float s = 0.f, s2 = 0.f;
    for (int r = threadIdx.x; r < Mrows; r += 256) {
        float vv = y[r*C + c];
        s += vv; s2 += vv*vv;
    }
    rs[threadIdx.x] = s; rs2[threadIdx.x] = s2;
    __syncthreads();
    for (int off = 128; off > 0; off >>= 1) {
        if (threadIdx.x < off) {
            rs[threadIdx.x]  += rs[threadIdx.x+off];
            rs2[threadIdx.x] += rs2[threadIdx.x+off];
        }
        __syncthreads();
    }
    if (threadIdx.x == 0) {
        float mean = rs[0] / (float)Mrows;
        float var  = rs2[0] / (float)Mrows - mean*mean;
        float a = gamma[c] * rsqrtf(var + EPS);
        a_out[c] = a;
        b_out[c] = beta[c] - mean*a;
    }
}

// ---------------- encoder layer 2: y2 = relu(bn(y1)) @ W_e2^T (64 -> 64) ----------------
__global__ __launch_bounds__(256) void enc2_kernel(const float* __restrict__ y1,
                                                   const float* __restrict__ a,
                                                   const float* __restrict__ b,
                                                   const float* __restrict__ W,
                                                   float* __restrict__ y2) {
    __shared__ float wt[4096];
    __shared__ float f[256];
    for (int i = threadIdx.x; i < 4096; i += 256)
        wt[(i & 63)*64 + (i >> 6)] = W[i];
    int lin = blockIdx.x*256 + threadIdx.x;
    int c0 = threadIdx.x & 63;
    f[threadIdx.x] = fmaxf(a[c0]*y1[lin] + b[c0], 0.0f);
    __syncthreads();
    int rloc = threadIdx.x >> 6, d = threadIdx.x & 63;
    const float* fr = f + rloc*64;
    float acc = 0.f;
    #pragma unroll 8
    for (int c = 0; c < 64; ++c) acc += fr[c] * wt[c*64 + d];
    y2[lin] = acc;
}

// ---------------- prepack W' = [Wl; Wr-Wl] as f16 [256][CIN] in global -------------
template<int CIN>
__global__ __launch_bounds__(256) void prepack_w_kernel(const float* __restrict__ W,  // 128 x 2*CIN
                                                        u16* __restrict__ W16) {      // 256 x CIN
    int i2 = blockIdx.x*256 + threadIdx.x;       // u32 index over 256*CIN/2
    int d = i2 / (CIN/2);
    int c = (i2 & (CIN/2 - 1)) * 2;
    float v0, v1;
    if (d < 128) {
        const float* wl = W + d*2*CIN;
        v0 = wl[c]; v1 = wl[c+1];
    } else {
        const float* wr = W + (d-128)*2*CIN;
        v0 = wr[CIN + c]   - wr[c];
        v1 = wr[CIN + c+1] - wr[c+1];
    }
    *(u32*)&W16[d*CIN + c] = f2h2(v0, v1);
}

// ---------------- uv via MFMA f16, register-B from prepacked W16 -------------------
template<int CIN, bool APPLY_BN>
__global__ __launch_bounds__(256) void uv_mfma_kernel(
        const float* __restrict__ fin,
        const float* __restrict__ a, const float* __restrict__ b,
        const u16* __restrict__ W16,    // 256 x CIN f16 (prepacked)
        u16* __restrict__ u, u16* __restrict__ v) {
    constexpr int PAD = CIN + 8;
    __shared__ u16 alds[32*PAD];
    const int t  = threadIdx.x;
    const int l  = t & 63;
    const int w  = t >> 6;      // wave -> output cols 64w..64w+63
    const int lr = l & 15;
    const int kg = l >> 4;

    // B fragments: rows w*64+ct*16+lr, col chunk kk*32+kg*8 (8 f16 = 16B)
    half8v bfrag[4][CIN/32];
    #pragma unroll
    for (int ct = 0; ct < 4; ++ct)
        #pragma unroll
        for (int kk = 0; kk < CIN/32; ++kk)
            bfrag[ct][kk] = *(const half8v*)&W16[(w*64 + ct*16 + lr)*CIN + kk*32 + kg*8];

    // stage A tile (32 rows), paired-u32 LDS writes, bn fused
    const int r0 = blockIdx.x * 32;
    for (int i2 = t; i2 < 32*(CIN/2); i2 += 256) {
        int r = i2 / (CIN/2);
        int c = (i2 & (CIN/2 - 1)) * 2;
        float2 vv = *(const float2*)&fin[(size_t)(r0 + r)*CIN + c];
        if (APPLY_BN) {
            float2 av = *(const float2*)&a[c];
            float2 bv = *(const float2*)&b[c];
            vv.x = fmaxf(av.x*vv.x + bv.x, 0.f);
            vv.y = fmaxf(av.y*vv.y + bv.y, 0.f);
        }
        *(u32*)&alds[r*PAD + c] = f2h2(vv.x, vv.y);
    }
    __syncthreads();

    f32x4 acc[2][4];
    #pragma unroll
    for (int rt = 0; rt < 2; ++rt)
        #pragma unroll
        for (int ct = 0; ct < 4; ++ct)
            acc[rt][ct] = (f32x4){0.f, 0.f, 0.f, 0.f};
    #pragma unroll
    for (int kk = 0; kk < CIN/32; ++kk) {
        const int ko = kk*32 + kg*8;
        half8v a0 = *(const half8v*)&alds[lr*PAD + ko];
        half8v a1 = *(const half8v*)&alds[(16 + lr)*PAD + ko];
        #pragma unroll
        for (int ct = 0; ct < 4; ++ct) {
            acc[0][ct] = __builtin_amdgcn_mfma_f32_16x16x32_f16(a0, bfrag[ct][kk], acc[0][ct], 0, 0, 0);
            acc[1][ct] = __builtin_amdgcn_mfma_f32_16x16x32_f16(a1, bfrag[ct][kk], acc[1][ct], 0, 0, 0);
        }
    }
    // write: C layout col=l&15, row=(l>>4)*4+e  [m89-verified]
    #pragma unroll
    for (int rt = 0; rt < 2; ++rt) {
        #pragma unroll
        for (int ct = 0; ct < 4; ++ct) {
            int col = w*64 + ct*16 + lr;            // wave-uniform side of 128 split
            u16* dst = (col < 128) ? u : v;
            int cc = col & 127;
            #pragma unroll
            for (int e = 0; e < 4; ++e) {
                int row = r0 + rt*16 + kg*4 + e;
                dst[(size_t)row*128 + cc] = f2h(acc[rt][ct][e]);
            }
        }
    }
}

// ---------------- stats of e = u[idx] + v over all (b,n,k), per channel (f16 in) ----
__global__ __launch_bounds__(256) void estats_kernel(const u16* __restrict__ u,
                                                     const u16* __restrict__ v,
                                                     const int* __restrict__ idx,
                                                     float* __restrict__ pS,
                                                     float* __restrict__ pS2) {
    __shared__ float red[4][132];
    const int t = threadIdx.x;
    const int l = t & 63;
    const int g = t >> 6;
    const int c2 = l*2;
    const int row0 = blockIdx.x * 256;
    float s0=0.f, s1=0.f, q0=0.f, q1=0.f;
    #pragma unroll 4
    for (int r = 0; r < 64; ++r) {
        int row = row0 + r*4 + g;
        int n = row >> 5;
        int j = idx[row];
        __half2 uh = *(const __half2*)&u[(size_t)j*128 + c2];
        __half2 vh = *(const __half2*)&v[(size_t)n*128 + c2];
        float2 ef = __half22float2(__hadd2(uh, vh));
        s0 += ef.x; q0 += ef.x*ef.x;
        s1 += ef.y; q1 += ef.y*ef.y;
    }
    red[g][c2] = s0; red[g][c2+1] = s1;
    __syncthreads();
    if (t < 128) pS[t*NBLK + blockIdx.x] = red[0][t]+red[1][t]+red[2][t]+red[3][t];
    __syncthreads();
    red[g][c2] = q0; red[g][c2+1] = q1;
    __syncthreads();
    if (t < 128) pS2[t*NBLK + blockIdx.x] = red[0][t]+red[1][t]+red[2][t]+red[3][t];
}

// ---------------- finalize BN coeffs: 128 blocks, coalesced channel-major reads -----
__global__ __launch_bounds__(256) void reduce_ab_kernel(const float* __restrict__ pS,
                                                        const float* __restrict__ pS2,
                                                        int nblk, float count,
                                                        const float* __restrict__ gamma,
                                                        const float* __restrict__ beta,
                                                        float* __restrict__ a_out,
                                                        float* __restrict__ b_out) {
    __shared__ double rs[256], rs2[256];
    const int c = blockIdx.x;
    const int t = threadIdx.x;
    double s = 0.0, s2 = 0.0;
    for (int i = t; i < nblk; i += 256) {
        s  += (double)pS [c*NBLK + i];
        s2 += (double)pS2[c*NBLK + i];
    }
    rs[t] = s; rs2[t] = s2;
    __syncthreads();
    for (int off = 128; off > 0; off >>= 1) {
        if (t < off) { rs[t] += rs[t+off]; rs2[t] += rs2[t+off]; }
        __syncthreads();
    }
    if (t == 0) {
        double mean = rs[0] / (double)count;
        double var  = rs2[0] / (double)count - mean*mean;
        float a = gamma[c] * (float)(1.0 / sqrt(var + (double)EPS));
        a_out[c] = a;
        b_out[c] = beta[c] - (float)mean * a;
    }
}

// ---------------- local_op heavy pass: bn2 stats AND per-point max in ONE pass ------
__device__ inline u32 bnrelu_pack(u32 uw, u32 vw, float a0, float b0, float a1, float b1) {
    float2 uf = h2f2(uw), vf = h2f2(vw);
    float h0 = fmaxf(a0*(uf.x + vf.x) + b0, 0.f);
    float h1 = fmaxf(a1*(uf.y + vf.y) + b1, 0.f);
    return f2h2(h0, h1);
}

__global__ __launch_bounds__(256, 3) void local_stats_max_kernel(
        const u16* __restrict__ u, const u16* __restrict__ v,
        const int* __restrict__ idx,
        const float* __restrict__ a1, const float* __restrict__ b1,
        const float* __restrict__ W2,          // 128x128 row-major [d][c]
        float* __restrict__ pS, float* __restrict__ pS2,
        float* __restrict__ M) {
    __shared__ u16 alds[2][32*136];   // f16 act [r][c], double-buffered (17.4 KB)
    const int t  = threadIdx.x;
    const int l  = t & 63;
    const int w  = t >> 6;       // wave 0..3 -> output cols 32w..32w+31
    const int lr = l & 15;
    const int kg = l >> 4;       // 0..3

    // B fragments global->reg (f32->f16 RNE)
    half8v bfrag[2][4];
    #pragma unroll
    for (int ct = 0; ct < 2; ++ct) {
        #pragma unroll
        for (int kk = 0; kk < 4; ++kk) {
            const float* wp = W2 + (w*32 + ct*16 + lr)*128 + kk*32 + kg*8;
            float4 w0 = *(const float4*)wp;
            float4 w1 = *(const float4*)(wp + 4);
            half8v h;
            h[0] = (_Float16)w0.x; h[1] = (_Float16)w0.y;
            h[2] = (_Float16)w0.z; h[3] = (_Float16)w0.w;
            h[4] = (_Float16)w1.x; h[5] = (_Float16)w1.y;
            h[6] = (_Float16)w1.z; h[7] = (_Float16)w1.w;
            bfrag[ct][kk] = h;
        }
    }

    const int sr = t >> 3;          // staging row 0..31
    const int sc = (t & 7) * 16;    // staging col base (16 channels)

    float a1v[16], b1v[16];
    #pragma unroll
    for (int i = 0; i < 16; ++i) { a1v[i] = a1[sc + i]; b1v[i] = b1[sc + i]; }

    float sacc[2] = {0.f, 0.f}, s2acc[2] = {0.f, 0.f};

    const int p0 = blockIdx.x * 8;

    auto stage = [&](int p, int bi) {
        int j = idx[p*KK + sr];
        const u32* up = (const u32*)(u + (size_t)j*128 + sc);
        const u32* vp = (const u32*)(v + (size_t)p*128 + sc);
        uint4 ua = *(const uint4*)up;
        uint4 ub = *(const uint4*)(up + 4);
        uint4 va = *(const uint4*)vp;
        uint4 vb = *(const uint4*)(vp + 4);
        uint4 w0, w1;
        w0.x = bnrelu_pack(ua.x, va.x, a1v[0],  b1v[0],  a1v[1],  b1v[1]);
        w0.y = bnrelu_pack(ua.y, va.y, a1v[2],  b1v[2],  a1v[3],  b1v[3]);
        w0.z = bnrelu_pack(ua.z, va.z, a1v[4],  b1v[4],  a1v[5],  b1v[5]);
        w0.w = bnrelu_pack(ua.w, va.w, a1v[6],  b1v[6],  a1v[7],  b1v[7]);
        w1.x = bnrelu_pack(ub.x, vb.x, a1v[8],  b1v[8],  a1v[9],  b1v[9]);
        w1.y = bnrelu_pack(ub.y, vb.y, a1v[10], b1v[10], a1v[11], b1v[11]);
        w1.z = bnrelu_pack(ub.z, vb.z, a1v[12], b1v[12], a1v[13], b1v[13]);
        w1.w = bnrelu_pack(ub.w, vb.w, a1v[14], b1v[14], a1v[15], b1v[15]);
        *(uint4*)(void*)&alds[bi][sr*136 + sc]     = w0;
        *(uint4*)(void*)&alds[bi][sr*136 + sc + 8] = w1;
    };

    stage(p0, 0);
    __syncthreads();

    for (int g = 0; g < 8; ++g) {
        const int p = p0 + g;
        if (g < 7) stage(p + 1, (g + 1) & 1);
        const u16* ab = alds[g & 1];
        f32x4 acc[2][2];
        #pragma unroll
        for (int rt = 0; rt < 2; ++rt)
            #pragma unroll
            for (int ct = 0; ct < 2; ++ct)
                acc[rt][ct] = (f32x4){0.f, 0.f, 0.f, 0.f};
        #pragma unroll
        for (int kk = 0; kk < 4; ++kk) {
            const int ko = kk*32 + kg*8;
            half8v a0  = *(const half8v*)&ab[lr*136 + ko];
            half8v a1f = *(const half8v*)&ab[(16 + lr)*136 + ko];
            acc[0][0] = __builtin_amdgcn_mfma_f32_16x16x32_f16(a0,  bfrag[0][kk], acc[0][0], 0, 0, 0);
            acc[1][0] = __builtin_amdgcn_mfma_f32_16x16x32_f16(a1f, bfrag[0][kk], acc[1][0], 0, 0, 0);
            acc[0][1] = __builtin_amdgcn_mfma_f32_16x16x32_f16(a0,  bfrag[1][kk], acc[0][1], 0, 0, 0);
            acc[1][1] = __builtin_amdgcn_mfma_f32_16x16x32_f16(a1f, bfrag[1][kk], acc[1][1], 0, 0, 0);
        }
        #pragma unroll
        for (int ct = 0; ct < 2; ++ct) {
            float s = 0.f, qq = 0.f;
            float m = acc[0][ct][0];
            #pragma unroll
            for (int rt = 0; rt < 2; ++rt)
                #pragma unroll
                for (int e = 0; e < 4; ++e) {
                    float h = acc[rt][ct][e];
                    s += h; qq += h*h;
                    m = fmaxf(m, h);
                }
            sacc[ct] += s; s2acc[ct] += qq;
            m = fmaxf(m, __shfl_xor(m, 16, 64));
            m = fmaxf(m, __shfl_xor(m, 32, 64));
            if (l < 16) M[(size_t)p*128 + w*32 + ct*16 + lr] = m;
        }
        __syncthreads();
    }
    #pragma unroll
    for (int ct = 0; ct < 2; ++ct) {
        float s = sacc[ct], qq = s2acc[ct];
        s  += __shfl_xor(s, 16, 64);  s  += __shfl_xor(s, 32, 64);
        qq += __shfl_xor(qq, 16, 64); qq += __shfl_xor(qq, 32, 64);
        if (l < 16) {
            pS [(w*32 + ct*16 + lr)*NBLK + blockIdx.x] = s;
            pS2[(w*32 + ct*16 + lr)*NBLK + blockIdx.x] = qq;
        }
    }
}

// ---------------- finalize: out = relu(a2*M + b2), elementwise MM x 128 -------------
__global__ __launch_bounds__(256) void finalize_kernel(const float* __restrict__ M,
                                                       const float* __restrict__ a2,
                                                       const float* __restrict__ b2,
                                                       float* __restrict__ outp) {
    int i = blockIdx.x*256 + threadIdx.x;   // float4 index over MM*32
    int c = (i & 31) * 4;
    float4 av = *(const float4*)&a2[c];
    float4 bv = *(const float4*)&b2[c];
    float4 m = ((const float4*)M)[i];
    m.x = fmaxf(av.x*m.x + bv.x, 0.f);
    m.y = fmaxf(av.y*m.y + bv.y, 0.f);
    m.z = fmaxf(av.z*m.z + bv.z, 0.f);
    m.w = fmaxf(av.w*m.w + bv.w, 0.f);
    ((float4*)outp)[i] = m;
}

// ---------------- host launcher ----------------
extern "C" void kernel_launch(void* const* d_in, const int* in_sizes, int n_in,
                              void* d_out, int out_size, void* d_ws, size_t ws_size,
                              hipStream_t stream) {
    const float* x     = (const float*)d_in[0];
    const float* W_e1  = (const float*)d_in[1];
    const float* g_e1  = (const float*)d_in[2];
    const float* b_e1  = (const float*)d_in[3];
    const float* W_e2  = (const float*)d_in[4];
    const float* g_e2  = (const float*)d_in[5];
    const float* b_e2  = (const float*)d_in[6];
    const float* W_l1a = (const float*)d_in[7];
    const float* g_l1a = (const float*)d_in[8];
    const float* b_l1a = (const float*)d_in[9];
    const float* W_l1b = (const float*)d_in[10];
    const float* g_l1b = (const float*)d_in[11];
    const float* b_l1b = (const float*)d_in[12];
    const float* W_l2a = (const float*)d_in[13];
    const float* g_l2a = (const float*)d_in[14];
    const float* b_l2a = (const float*)d_in[15];
    const float* W_l2b = (const float*)d_in[16];
    const float* g_l2b = (const float*)d_in[17];
    const float* b_l2b = (const float*)d_in[18];

    float* ws   = (float*)d_ws;
    int*   idx  = (int*)(ws + OFF_IDX);
    float* y1   = ws + OFF_Y1;
    float* y2   = ws + OFF_Y2;
    u16*   u    = (u16*)(ws + OFF_U);
    u16*   v    = (u16*)(ws + OFF_V);
    float* M1   = ws + OFF_Y1;     // reuses Y1+Y2 (dead after uv1)
    float* M2   = ws + OFF_F2;
    float* pS   = ws + OFF_PS;
    float* pS2  = ws + OFF_PS2;
    u16*   W16  = (u16*)(ws + OFF_PS);   // aliased: live only prepack->uv (estats clobbers after)
    float* ab   = ws + OFF_AB;
    float *a_e1 = ab,        *be1 = ab + 128,
          *a_e2 = ab + 256,  *be2 = ab + 384,
          *a_1a = ab + 512,  *b_1a = ab + 640,
          *a_1b = ab + 768,  *b_1b = ab + 896,
          *a_2a = ab + 1024, *b_2a = ab + 1152,
          *a_2b = ab + 1280, *b_2b = ab + 1408;

    knn_kernel<<<dim3(MM/8), dim3(256), 0, stream>>>(x, idx);

    enc1_kernel<<<dim3(MM*64/256), dim3(256), 0, stream>>>(x, W_e1, y1);
    colstats_kernel<<<dim3(64), dim3(256), 0, stream>>>(y1, MM, 64, g_e1, b_e1, a_e1, be1);
    enc2_kernel<<<dim3(MM*64/256), dim3(256), 0, stream>>>(y1, a_e1, be1, W_e2, y2);
    colstats_kernel<<<dim3(64), dim3(256), 0, stream>>>(y2, MM, 64, g_e2, b_e2, a_e2, be2);

    // ---- local_op 1 ----
    prepack_w_kernel<64><<<dim3(32), dim3(256), 0, stream>>>(W_l1a, W16);
    uv_mfma_kernel<64, true><<<dim3(MM/32), dim3(256), 0, stream>>>(y2, a_e2, be2, W16, u, v);
    estats_kernel<<<dim3(LL/256), dim3(256), 0, stream>>>(u, v, idx, pS, pS2);
    reduce_ab_kernel<<<dim3(128), dim3(256), 0, stream>>>(pS, pS2, LL/256, (float)LL, g_l1a, b_l1a, a_1a, b_1a);
    local_stats_max_kernel<<<dim3(MM/8), dim3(256), 0, stream>>>(u, v, idx, a_1a, b_1a, W_l1b, pS, pS2, M1);
    reduce_ab_kernel<<<dim3(128), dim3(256), 0, stream>>>(pS, pS2, MM/8, (float)LL, g_l1b, b_l1b, a_1b, b_1b);

    // ---- local_op 2 (finalize#1 fused into uv A-load) ----
    prepack_w_kernel<128><<<dim3(64), dim3(256), 0, stream>>>(W_l2a, W16);
    uv_mfma_kernel<128, true><<<dim3(MM/32), dim3(256), 0, stream>>>(M1, a_1b, b_1b, W16, u, v);
    estats_kernel<<<dim3(LL/256), dim3(256), 0, stream>>>(u, v, idx, pS, pS2);
    reduce_ab_kernel<<<dim3(128), dim3(256), 0, stream>>>(pS, pS2, LL/256, (float)LL, g_l2a, b_l2a, a_2a, b_2a);
    local_stats_max_kernel<<<dim3(MM/8), dim3(256), 0, stream>>>(u, v, idx, a_2a, b_2a, W_l2b, pS, pS2, M2);
    reduce_ab_kernel<<<dim3(128), dim3(256), 0, stream>>>(pS, pS2, MM/8, (float)LL, g_l2b, b_l2b, a_2b, b_2b);
    finalize_kernel<<<dim3(MM*32/256), dim3(256), 0, stream>>>(M2, a_2b, b_2b, (float*)d_out);
}